// Round 6
// baseline (299.403 us; speedup 1.0000x reference)
//
#include <hip/hip_runtime.h>
#include <math.h>

#define NNB   576          // sequence length N
#define BNR   4608         // B*N rows
#define KSEL  51           // top-k along D

typedef unsigned short u16;
typedef __attribute__((ext_vector_type(8))) short bf16x8;
typedef __attribute__((ext_vector_type(4))) float f32x4;

// round-to-nearest (ties up) f32 -> bf16; inputs are finite
__device__ __forceinline__ u16 f2bf(float f) {
    unsigned u = __float_as_uint(f);
    return (u16)((u + 0x8000u) >> 16);
}
__device__ __forceinline__ unsigned pack2(float a, float b) {
    unsigned ua = __float_as_uint(a), ub = __float_as_uint(b);
    return ((ua + 0x8000u) >> 16) | ((ub + 0x8000u) & 0xffff0000u);
}
// async global->LDS DMA, 16B per lane; LDS dst = base + lane*16 (wave-uniform base)
__device__ __forceinline__ void load_lds16(const void* gp, void* lp) {
    __builtin_amdgcn_global_load_lds((const __attribute__((address_space(1))) void*)gp,
                                     (__attribute__((address_space(3))) void*)lp, 16, 0, 0);
}
// full-wave64 sum via DPP (row_shr 1/2/4/8, bcast15, bcast31), result uniform
__device__ __forceinline__ float dpp_red_add_f(float x) {
    x += __int_as_float(__builtin_amdgcn_update_dpp(0, __float_as_int(x), 0x111, 0xf, 0xf, true));
    x += __int_as_float(__builtin_amdgcn_update_dpp(0, __float_as_int(x), 0x112, 0xf, 0xf, true));
    x += __int_as_float(__builtin_amdgcn_update_dpp(0, __float_as_int(x), 0x114, 0xf, 0xf, true));
    x += __int_as_float(__builtin_amdgcn_update_dpp(0, __float_as_int(x), 0x118, 0xf, 0xf, true));
    x += __int_as_float(__builtin_amdgcn_update_dpp(0, __float_as_int(x), 0x142, 0xa, 0xf, true));
    x += __int_as_float(__builtin_amdgcn_update_dpp(0, __float_as_int(x), 0x143, 0xc, 0xf, true));
    return __int_as_float(__builtin_amdgcn_readlane(__float_as_int(x), 63));
}
// wave-wide boolean count: v_cmp -> sgpr-pair ballot, counted on the SALU pipe
__device__ __forceinline__ int wave_cnt(bool p) {
    return __popcll(__ballot(p));
}

// ---------------------------------------------------------------------------
// Cast F, in_proj_w, out_proj_w, w1 to bf16 (segment boundaries block-aligned)
// ---------------------------------------------------------------------------
__global__ __launch_bounds__(256)
void cast_bf16(const float* __restrict__ F, const float* __restrict__ ipw,
               const float* __restrict__ opw, const float* __restrict__ w1,
               u16* __restrict__ Fb, u16* __restrict__ ipwb,
               u16* __restrict__ opwb, u16* __restrict__ w1b)
{
    size_t i4 = ((size_t)blockIdx.x * 256 + threadIdx.x) * 4;
    const float* src; u16* dst; size_t off;
    if      (i4 < 2359296) { src = F;   dst = Fb;   off = i4; }
    else if (i4 < 3145728) { src = ipw; dst = ipwb; off = i4 - 2359296; }
    else if (i4 < 3407872) { src = opw; dst = opwb; off = i4 - 3145728; }
    else                   { src = w1;  dst = w1b;  off = i4 - 3407872; }
    float4 v = *(const float4*)(src + off);
    uint2 o; o.x = pack2(v.x, v.y); o.y = pack2(v.z, v.w);
    *(uint2*)(dst + off) = o;
}

// ---------------------------------------------------------------------------
// qkv GEMM: bf16 MFMA, 128x128 tile, BK=64. 4 waves in 2x2, each owns a
// 64x64 sub-tile (4x4 fragments, 32 MFMA per K-step). Grid 432 blocks.
// Cols<512 scaled by log2(e)/8 (attention prescale, exp2 downstream).
// ---------------------------------------------------------------------------
__global__ __launch_bounds__(256, 2)
void gemm_qkv128(const u16* __restrict__ A, const u16* __restrict__ Bw,
                 const float* __restrict__ bias, u16* __restrict__ C,
                 int Nc, int Kd)
{
    __shared__ uint4 As4[1024];          // 128 rows x 64 k bf16 = 16 KB
    __shared__ uint4 Bs4[1024];
    const int tid = threadIdx.x;
    const int lane = tid & 63, w = tid >> 6;
    const int wu = __builtin_amdgcn_readfirstlane(w);
    const int r16 = lane & 15, quad = lane >> 4;
    const int wy = w >> 1, wx = w & 1;
    const int c0 = blockIdx.x << 7, r0 = blockIdx.y << 7;

    const u16* pA[4]; const u16* pB[4];
    #pragma unroll
    for (int rd = 0; rd < 4; ++rd) {
        const int c = (rd << 8) + tid;            // 0..1023
        const int kb = c >> 9, g = (c >> 6) & 7, rr = (c >> 2) & 15, q = c & 3;
        const int row = (g << 4) + rr;
        const int koff = (kb << 5) + (q << 3);
        pA[rd] = A  + (size_t)(r0 + row) * Kd + koff;
        pB[rd] = Bw + (size_t)(c0 + row) * Kd + koff;
    }

    f32x4 acc[4][4];
    #pragma unroll
    for (int i = 0; i < 4; ++i)
        #pragma unroll
        for (int j = 0; j < 4; ++j) acc[i][j] = (f32x4){0.f, 0.f, 0.f, 0.f};

    for (int kk = 0; kk < Kd; kk += 64) {
        __syncthreads();
        #pragma unroll
        for (int rd = 0; rd < 4; ++rd) {
            load_lds16(pA[rd] + kk, (void*)(As4 + (rd << 8) + (wu << 6)));
            load_lds16(pB[rd] + kk, (void*)(Bs4 + (rd << 8) + (wu << 6)));
        }
        __syncthreads();
        #pragma unroll
        for (int kb = 0; kb < 2; ++kb) {
            bf16x8 af[4], bfr[4];
            #pragma unroll
            for (int i = 0; i < 4; ++i)
                af[i] = *(const bf16x8*)&As4[((kb * 8 + (wy << 2) + i) << 6) + (r16 << 2) + quad];
            #pragma unroll
            for (int j = 0; j < 4; ++j)
                bfr[j] = *(const bf16x8*)&Bs4[((kb * 8 + (wx << 2) + j) << 6) + (r16 << 2) + quad];
            #pragma unroll
            for (int i = 0; i < 4; ++i)
                #pragma unroll
                for (int j = 0; j < 4; ++j)
                    acc[i][j] = __builtin_amdgcn_mfma_f32_16x16x32_bf16(af[i], bfr[j], acc[i][j], 0, 0, 0);
        }
    }

    float bcol[4], scl[4];
    #pragma unroll
    for (int j = 0; j < 4; ++j) {
        const int col = c0 + (wx << 6) + (j << 4) + r16;
        bcol[j] = bias[col];
        scl[j] = (col < 512) ? 0.180336880111120426f : 1.0f;   // log2(e)/8
    }
    #pragma unroll
    for (int i = 0; i < 4; ++i) {
        #pragma unroll
        for (int reg = 0; reg < 4; ++reg) {
            const int row = r0 + (wy << 6) + (i << 4) + (quad << 2) + reg;
            const size_t base = (size_t)row * Nc;
            #pragma unroll
            for (int j = 0; j < 4; ++j) {
                const int col = c0 + (wx << 6) + (j << 4) + r16;
                float v = (acc[i][j][reg] + bcol[j]) * scl[j];
                C[base + col] = f2bf(v);
            }
        }
    }
}

// ---------------------------------------------------------------------------
// bf16 MFMA GEMM, 64x64 tile, BK=64: 576 blocks for the Nc=512 GEMMs.
// Waves 2x2, each 32x32 (2x2 frags, 16 acc VGPRs). Serial DMA staging.
// ---------------------------------------------------------------------------
template<bool RESID, bool OUT_BF16>
__global__ __launch_bounds__(256)
void gemm_6464(const u16* __restrict__ A, const u16* __restrict__ Bw,
               const float* __restrict__ bias, const float* __restrict__ res,
               void* __restrict__ Cv, int Mr, int Nc, int Kd)
{
    __shared__ uint4 As4[512];
    __shared__ uint4 Bs4[512];
    const int tid = threadIdx.x;
    const int lane = tid & 63, w = tid >> 6;
    const int wu = __builtin_amdgcn_readfirstlane(w);
    const int r16 = lane & 15, quad = lane >> 4;
    const int wy = w >> 1, wx = w & 1;
    const int r0 = blockIdx.y << 6, c0 = blockIdx.x << 6;

    const u16* pA[2]; const u16* pB[2];
    #pragma unroll
    for (int rd = 0; rd < 2; ++rd) {
        const int c = (rd << 8) + tid;            // 0..511
        const int kb = c >> 8, g = (c >> 6) & 3, rr = (c >> 2) & 15, q = c & 3;
        const int row = (g << 4) + rr;
        const int koff = (kb << 5) + (q << 3);
        pA[rd] = A  + (size_t)(r0 + row) * Kd + koff;
        pB[rd] = Bw + (size_t)(c0 + row) * Kd + koff;
    }

    f32x4 acc[2][2];
    #pragma unroll
    for (int i = 0; i < 2; ++i)
        #pragma unroll
        for (int j = 0; j < 2; ++j) acc[i][j] = (f32x4){0.f, 0.f, 0.f, 0.f};

    for (int kk = 0; kk < Kd; kk += 64) {
        __syncthreads();
        #pragma unroll
        for (int rd = 0; rd < 2; ++rd) {
            load_lds16(pA[rd] + kk, (void*)(As4 + (rd << 8) + (wu << 6)));
            load_lds16(pB[rd] + kk, (void*)(Bs4 + (rd << 8) + (wu << 6)));
        }
        __syncthreads();
        #pragma unroll
        for (int kb = 0; kb < 2; ++kb) {
            bf16x8 af[2], bfr[2];
            #pragma unroll
            for (int i = 0; i < 2; ++i)
                af[i] = *(const bf16x8*)&As4[((kb * 4 + (wy << 1) + i) << 6) + (r16 << 2) + quad];
            #pragma unroll
            for (int j = 0; j < 2; ++j)
                bfr[j] = *(const bf16x8*)&Bs4[((kb * 4 + (wx << 1) + j) << 6) + (r16 << 2) + quad];
            #pragma unroll
            for (int i = 0; i < 2; ++i)
                #pragma unroll
                for (int j = 0; j < 2; ++j)
                    acc[i][j] = __builtin_amdgcn_mfma_f32_16x16x32_bf16(af[i], bfr[j], acc[i][j], 0, 0, 0);
        }
    }

    float bcol[2];
    #pragma unroll
    for (int j = 0; j < 2; ++j) bcol[j] = bias[c0 + (wx << 5) + (j << 4) + r16];
    #pragma unroll
    for (int i = 0; i < 2; ++i) {
        #pragma unroll
        for (int reg = 0; reg < 4; ++reg) {
            const int row = r0 + (wy << 5) + (i << 4) + (quad << 2) + reg;
            const size_t base = (size_t)row * Nc;
            #pragma unroll
            for (int j = 0; j < 2; ++j) {
                const int col = c0 + (wx << 5) + (j << 4) + r16;
                float v = acc[i][j][reg] + bcol[j];
                if (RESID) v += res[base + col];
                if (OUT_BF16) ((u16*)Cv)[base + col] = f2bf(v);
                else          ((float*)Cv)[base + col] = v;
            }
        }
    }
}

// ---------------------------------------------------------------------------
// bf16 MFMA flash attention, no-max softmax (q prescaled by log2e/8 -> exp2).
// K via DMA. V scatter paired as ds_write_b32; Vfs XOR-swizzled, Pfs
// digit-permuted (both <=4-way conflicts).
// ---------------------------------------------------------------------------
__global__ __launch_bounds__(256)
void attn_mfma(const u16* __restrict__ qkv, u16* __restrict__ obuf)
{
    __shared__ uint4 Qf[512];
    __shared__ uint4 Kf[512];
    __shared__ u16  Vfs[4096];
    __shared__ u16  Pfs[4096];
    const int tid = threadIdx.x;
    const int lane = tid & 63, w = tid >> 6;
    const int wu = __builtin_amdgcn_readfirstlane(w);
    const int r16 = lane & 15, quad = lane >> 4;
    const int b = blockIdx.y >> 3, h = blockIdx.y & 7;
    const int i0 = blockIdx.x << 6;
    const u16* qb = qkv + (size_t)b * NNB * 1536 + h * 64;

    #pragma unroll
    for (int s = 0; s < 2; ++s) {        // stage Q once
        const int linear = (s << 8) + tid;
        const int r = linear >> 3, q7 = linear & 7;
        uint4 v = *(const uint4*)(qb + (size_t)(i0 + r) * 1536 + (q7 << 3));
        Qf[(((q7 >> 2) * 4 + (r >> 4)) << 6) + ((r & 15) << 2) + (q7 & 3)] = v;
    }
    const u16* pK[2];
    #pragma unroll
    for (int rd = 0; rd < 2; ++rd) {
        const int c = (rd << 8) + tid;
        const int kb = c >> 8, g = (c >> 6) & 3, rr = (c >> 2) & 15, q = c & 3;
        pK[rd] = qb + 512 + (size_t)((g << 4) + rr) * 1536 + (kb << 5) + (q << 3);
    }
    const int vp = tid >> 3, vq7 = tid & 7;     // V pair id / d-slice
    const int vj = vp << 1;
    const int vjl2 = (vj & 7) >> 1, vjq = (vj >> 3) & 3, vjkb = vj >> 5;

    float l_i[4] = {0.f, 0.f, 0.f, 0.f};
    f32x4 accO[4];
    #pragma unroll
    for (int f = 0; f < 4; ++f) accO[f] = (f32x4){0.f, 0.f, 0.f, 0.f};

    for (int j0 = 0; j0 < NNB; j0 += 64) {
        const u16* vbase = qb + 1024 + (size_t)(j0 + vj) * 1536 + (vq7 << 3);
        uint4 vA = *(const uint4*)vbase;
        uint4 vB = *(const uint4*)(vbase + 1536);
        __syncthreads();                 // previous iter's readers done
        load_lds16(pK[0] + (size_t)j0 * 1536, (void*)(Kf + (wu << 6)));
        load_lds16(pK[1] + (size_t)j0 * 1536, (void*)(Kf + 256 + (wu << 6)));
        {
            const u16* ea = (const u16*)&vA;
            const u16* eb = (const u16*)&vB;
            unsigned* V32 = (unsigned*)Vfs;
            #pragma unroll
            for (int e = 0; e < 8; ++e) {
                const int d = (vq7 << 3) + e;
                const int g = d >> 4;
                const int ch = ((vjkb * 4 + g) << 6) + ((((d & 15) << 2) + vjq) ^ g);
                V32[(ch << 2) + vjl2] = (unsigned)ea[e] | ((unsigned)eb[e] << 16);
            }
        }
        __syncthreads();

        f32x4 accS[4];
        #pragma unroll
        for (int f = 0; f < 4; ++f) accS[f] = (f32x4){0.f, 0.f, 0.f, 0.f};
        #pragma unroll
        for (int kb = 0; kb < 2; ++kb) {
            bf16x8 aq = *(const bf16x8*)&Qf[((kb * 4 + w) << 6) + (r16 << 2) + quad];
            #pragma unroll
            for (int f = 0; f < 4; ++f) {
                bf16x8 bk = *(const bf16x8*)&Kf[((kb * 4 + f) << 6) + (r16 << 2) + quad];
                accS[f] = __builtin_amdgcn_mfma_f32_16x16x32_bf16(aq, bk, accS[f], 0, 0, 0);
            }
        }
        #pragma unroll
        for (int reg = 0; reg < 4; ++reg) {
            const float s0 = exp2f(accS[0][reg]);
            const float s1 = exp2f(accS[1][reg]);
            const float s2 = exp2f(accS[2][reg]);
            const float s3 = exp2f(accS[3][reg]);
            l_i[reg] += (s0 + s1) + (s2 + s3);
            const int m = (quad << 2) + reg;
            const int sm = ((m & 3) << 2) + (m >> 2);     // digit-permuted m
            const float pv[4] = {s0, s1, s2, s3};
            #pragma unroll
            for (int f = 0; f < 4; ++f) {
                const int k = (f << 4) + r16;
                const int ch = (((k >> 5) * 4 + w) << 6) + (((k >> 3) & 3) << 4) + sm;
                Pfs[(ch << 3) + (k & 7)] = f2bf(pv[f]);
            }
        }
        #pragma unroll
        for (int kb = 0; kb < 2; ++kb) {
            bf16x8 ap = *(const bf16x8*)&Pfs[((((kb * 4 + w) << 6) + (quad << 4) + ((r16 & 3) << 2) + (r16 >> 2)) << 3)];
            #pragma unroll
            for (int f = 0; f < 4; ++f) {
                bf16x8 bv = *(const bf16x8*)&Vfs[((((kb * 4 + f) << 6) + (((r16 << 2) + quad) ^ f)) << 3)];
                accO[f] = __builtin_amdgcn_mfma_f32_16x16x32_bf16(ap, bv, accO[f], 0, 0, 0);
            }
        }
    }
    #pragma unroll
    for (int reg = 0; reg < 4; ++reg) {
        float l = l_i[reg];
        l += __shfl_xor(l, 1); l += __shfl_xor(l, 2);
        l += __shfl_xor(l, 4); l += __shfl_xor(l, 8);
        const float inv = 1.0f / l;
        const size_t row = (size_t)(b * NNB + i0 + (w << 4) + (quad << 2) + reg);
        #pragma unroll
        for (int f = 0; f < 4; ++f)
            obuf[row * 512 + (h << 6) + (f << 4) + r16] = f2bf(accO[f][reg] * inv);
    }
}

// ---------------------------------------------------------------------------
// Fused: LN+GELU -> comp -> exact top-51 -> direct sparse write.
// TWO bn-rows per block (grid 2304): each thread carries two independent
// copies of every serial chain (erff, DPP trees, L2 loads, ballot rounds)
// interleaved for latency hiding, and w2/T weight loads are shared across
// the row pair (halves per-row L2 traffic). Per-row arithmetic executes in
// the exact op order of the 1-row version -> bit-identical output.
// Rationale: counters show all pipes idle (VALU 45%, HBM 20%, MFMA 0) ->
// latency-bound; r3 showed more waves doesn't help; this adds ILP instead.
// ---------------------------------------------------------------------------
__global__ __launch_bounds__(256)
void outer_topk(const float* __restrict__ F, const float* __restrict__ hraw,
                const float* __restrict__ lng, const float* __restrict__ lnb,
                const float* __restrict__ w2, const float* __restrict__ b2,
                const float* __restrict__ T, float* __restrict__ out)
{
    const int bn0 = blockIdx.x << 1;
    const int tid = threadIdx.x;
    const int lane = tid & 63, w = tid >> 6;
    __shared__ float Fr[2][512];
    __shared__ float Hr[2][512];
    __shared__ unsigned keyslots[4][4][64];   // per-wave scratch, reused per row
    __shared__ float redsm[16];

    // --- load both F rows + both raw h rows; LN + exact GELU into Hr ---
    if (tid < 128) {
        *(float4*)&Fr[0][tid << 2] = *(const float4*)(F + (size_t)bn0 * 512 + (tid << 2));
        *(float4*)&Fr[1][tid << 2] = *(const float4*)(F + (size_t)(bn0 + 1) * 512 + (tid << 2));
    }
    const float* hp0 = hraw + (size_t)bn0 * 512;
    const float* hp1 = hp0 + 512;
    const float a0 = hp0[tid], a1 = hp0[tid + 256];
    const float c0_ = hp1[tid], c1_ = hp1[tid + 256];
    float sw0 = dpp_red_add_f(a0 + a1);
    float sq0 = dpp_red_add_f(a0 * a0 + a1 * a1);
    float sw1 = dpp_red_add_f(c0_ + c1_);
    float sq1 = dpp_red_add_f(c0_ * c0_ + c1_ * c1_);
    if (lane == 0) {
        redsm[w] = sw0; redsm[4 + w] = sq0;
        redsm[8 + w] = sw1; redsm[12 + w] = sq1;
    }
    __syncthreads();
    const float s0 = redsm[0] + redsm[1] + redsm[2] + redsm[3];
    const float q0 = redsm[4] + redsm[5] + redsm[6] + redsm[7];
    const float s1 = redsm[8] + redsm[9] + redsm[10] + redsm[11];
    const float q1 = redsm[12] + redsm[13] + redsm[14] + redsm[15];
    const float mean0 = s0 * (1.0f / 512.0f);
    const float var0  = q0 * (1.0f / 512.0f) - mean0 * mean0;
    const float rstd0 = rsqrtf(var0 + 1e-5f);
    const float mean1 = s1 * (1.0f / 512.0f);
    const float var1  = q1 * (1.0f / 512.0f) - mean1 * mean1;
    const float rstd1 = rsqrtf(var1 + 1e-5f);
    const float g0 = lng[tid], g1 = lng[tid + 256];     // shared across rows
    const float o0 = lnb[tid], o1 = lnb[tid + 256];
    float y;
    y = (a0 - mean0) * rstd0 * g0 + o0;
    Hr[0][tid]       = 0.5f * y * (1.0f + erff(y * 0.70710678118654752f));
    y = (a1 - mean0) * rstd0 * g1 + o1;
    Hr[0][tid + 256] = 0.5f * y * (1.0f + erff(y * 0.70710678118654752f));
    y = (c0_ - mean1) * rstd1 * g0 + o0;
    Hr[1][tid]       = 0.5f * y * (1.0f + erff(y * 0.70710678118654752f));
    y = (c1_ - mean1) * rstd1 * g1 + o1;
    Hr[1][tid + 256] = 0.5f * y * (1.0f + erff(y * 0.70710678118654752f));
    __syncthreads();

    // --- comp[m] = Hr . w2[m] + b2[m]; w2 loads shared across the row pair ---
    const int m0 = w << 2;
    float cm[2][4];
    #pragma unroll
    for (int mi = 0; mi < 4; ++mi) {
        const float* w2p = w2 + (size_t)(m0 + mi) * 512;
        float pa = 0.f, pb = 0.f;
        #pragma unroll
        for (int t = 0; t < 8; ++t) {
            const float wv = w2p[lane + (t << 6)];
            pa += Hr[0][lane + (t << 6)] * wv;
            pb += Hr[1][lane + (t << 6)] * wv;
        }
        const float bb = b2[m0 + mi];
        cm[0][mi] = dpp_red_add_f(pa) + bb;
        cm[1][mi] = dpp_red_add_f(pb) + bb;
    }

    // --- abs bit patterns + sign masks; T loads shared across the row pair ---
    unsigned u[2][4][8]; unsigned smask[2][4];
    #pragma unroll
    for (int mi = 0; mi < 4; ++mi) {
        smask[0][mi] = 0u; smask[1][mi] = 0u;
        const float* Tp = T + (size_t)(m0 + mi) * 512;
        #pragma unroll
        for (int t = 0; t < 8; ++t) {
            const float tv = Tp[lane + (t << 6)];
            float pp = Fr[0][lane + (t << 6)] * tv;
            float pc = pp * cm[0][mi];
            unsigned bits = __float_as_uint(pc);
            u[0][mi][t] = bits & 0x7fffffffu;
            smask[0][mi] |= (bits >> 31) << t;
            pp = Fr[1][lane + (t << 6)] * tv;
            pc = pp * cm[1][mi];
            bits = __float_as_uint(pc);
            u[1][mi][t] = bits & 0x7fffffffu;
            smask[1][mi] |= (bits >> 31) << t;
        }
    }

    // --- phase A: bisect exponent bits 30..23; 8 independent chains ---
    unsigned pref[2][4] = {{0u,0u,0u,0u},{0u,0u,0u,0u}};
    int cntP[2][4] = {{512,512,512,512},{512,512,512,512}};
    int U[2][4] = {{0,0,0,0},{0,0,0,0}};
    for (int bit = 30; bit >= 23; --bit) {
        const unsigned msk = 1u << bit;
        #pragma unroll
        for (int r = 0; r < 2; ++r)
            #pragma unroll
            for (int mi = 0; mi < 4; ++mi) {
                const unsigned cand = pref[r][mi] | msk;
                int cnt = 0;
                #pragma unroll
                for (int t = 0; t < 8; ++t) cnt += wave_cnt(u[r][mi][t] >= cand);
                if (cnt >= KSEL) { pref[r][mi] = cand; cntP[r][mi] = cnt; }
                else U[r][mi] = cnt;
            }
    }
    // rare: extend bisection until the tie bucket fits in 64 slots
    int blo[2][4];
    #pragma unroll
    for (int r = 0; r < 2; ++r)
        #pragma unroll
        for (int mi = 0; mi < 4; ++mi) {
            int b = 23;
            while ((cntP[r][mi] - U[r][mi]) > 64 && b > 0) {
                --b;
                const unsigned cand = pref[r][mi] | (1u << b);
                int cnt = 0;
                #pragma unroll
                for (int t = 0; t < 8; ++t) cnt += wave_cnt(u[r][mi][t] >= cand);
                if (cnt >= KSEL) { pref[r][mi] = cand; cntP[r][mi] = cnt; }
                else U[r][mi] = cnt;
            }
            blo[r][mi] = b;
        }
    int need[2][4];
    unsigned donemask = 0u;
    #pragma unroll
    for (int r = 0; r < 2; ++r)
        #pragma unroll
        for (int mi = 0; mi < 4; ++mi) {
            need[r][mi] = KSEL - U[r][mi];
            if (need[r][mi] == cntP[r][mi] - U[r][mi])   // whole bucket selected
                donemask |= 1u << ((r << 2) + mi);
        }

    // --- compact tie buckets into distinct 32-bit keys (scratch reused
    //     across rows; per-wave private slice, no barrier needed) ---
    const unsigned long long lmask = (1ull << lane) - 1ull;
    unsigned kv[2][4] = {{0u,0u,0u,0u},{0u,0u,0u,0u}};
    for (int r = 0; r < 2; ++r) {
        #pragma unroll
        for (int mi = 0; mi < 4; ++mi) {
            if (donemask & (1u << ((r << 2) + mi))) continue;
            keyslots[w][mi][lane] = 0u;
            const int bl = blo[r][mi];
            const unsigned lowmask = (1u << bl) - 1u;
            int running = 0;
            #pragma unroll
            for (int t = 0; t < 8; ++t) {
                const bool tie = ((u[r][mi][t] ^ pref[r][mi]) >> bl) == 0u;
                const unsigned long long M = __ballot(tie);
                const int slot = running + __popcll(M & lmask);
                if (tie && slot < 64) {
                    const unsigned key = ((u[r][mi][t] & lowmask) << 9) | (unsigned)(511 - ((t << 6) + lane));
                    keyslots[w][mi][slot] = key;
                }
                running += __popcll(M);
            }
            kv[r][mi] = keyslots[w][mi][lane];
        }
    }

    // --- phase B: bisect keys, 8 interleaved chains, early exit ---
    unsigned prefk[2][4] = {{0u,0u,0u,0u},{0u,0u,0u,0u}};
    for (int bb = 31; bb >= 0; --bb) {
        if (donemask == 0xffu) break;
        #pragma unroll
        for (int r = 0; r < 2; ++r)
            #pragma unroll
            for (int mi = 0; mi < 4; ++mi) {
                if (donemask & (1u << ((r << 2) + mi))) continue;
                const unsigned candk = prefk[r][mi] | (1u << bb);
                const int c = __popcll(__ballot(kv[r][mi] >= candk));
                if (c >= need[r][mi]) {
                    prefk[r][mi] = candk;
                    if (c == need[r][mi]) donemask |= 1u << ((r << 2) + mi);
                }
            }
    }

    // --- per-wave direct write of its 4 m-columns for both rows ---
    #pragma unroll
    for (int r = 0; r < 2; ++r) {
        float* ob = out + (size_t)(bn0 + r) * 8192 + m0;
        #pragma unroll
        for (int t = 0; t < 8; ++t) {
            const int d = (t << 6) + lane;
            float4 v;
            float* vv = &v.x;
            #pragma unroll
            for (int mi = 0; mi < 4; ++mi) {
                const unsigned uu = u[r][mi][t];
                const int bl = blo[r][mi];
                const bool tie = ((uu ^ pref[r][mi]) >> bl) == 0u;
                const unsigned key = ((uu & ((1u << bl) - 1u)) << 9) | (unsigned)(511 - d);
                const bool sel = (uu >= pref[r][mi] + (1u << bl)) || (tie && key >= prefk[r][mi]);
                const unsigned bits = uu | (((smask[r][mi] >> t) & 1u) << 31);
                vv[mi] = sel ? __uint_as_float(bits) : 0.0f;
            }
            *(float4*)(ob + (size_t)d * 16) = v;
        }
    }
}

// ---------------------------------------------------------------------------
extern "C" void kernel_launch(void* const* d_in, const int* in_sizes, int n_in,
                              void* d_out, int out_size, void* d_ws, size_t ws_size,
                              hipStream_t stream)
{
    const float* F    = (const float*)d_in[0];
    const float* ipw  = (const float*)d_in[1];
    const float* ipb  = (const float*)d_in[2];
    const float* opw  = (const float*)d_in[3];
    const float* opb  = (const float*)d_in[4];
    const float* w1   = (const float*)d_in[5];
    const float* b1   = (const float*)d_in[6];
    const float* lng  = (const float*)d_in[7];
    const float* lnb  = (const float*)d_in[8];
    const float* w2   = (const float*)d_in[9];
    const float* b2   = (const float*)d_in[10];
    const float* tmpl = (const float*)d_in[11];

    char* wsb = (char*)d_ws;
    u16*   qkvb  = (u16*)wsb;                     // 4608*1536 bf16
    u16*   obufb = (u16*)(wsb + 14155776);        // 4608*512 bf16
    u16*   fenhb = (u16*)(wsb + 18874368);        // 4608*512 bf16
    float* hbuf  = (float*)(wsb + 23592960);      // 4608*512 f32 (raw, pre-LN)
    u16*   Fbf   = (u16*)(wsb + 33030144);        // 4608*512 bf16
    u16*   ipwbf = (u16*)(wsb + 37748736);        // 1536*512 bf16
    u16*   opwbf = (u16*)(wsb + 39321600);        // 512*512 bf16
    u16*   w1bf  = (u16*)(wsb + 39845888);        // 512*512 bf16

    cast_bf16<<<3584, 256, 0, stream>>>(F, ipw, opw, w1, Fbf, ipwbf, opwbf, w1bf);
    // qkv = F @ ipw^T + ipb (q prescaled by log2e/8) -> bf16, 432 blocks
    gemm_qkv128<<<dim3(12, 36), 256, 0, stream>>>(Fbf, ipwbf, ipb, qkvb, 1536, 512);
    // o = attention(qkv) -> bf16 [4608,512]
    attn_mfma<<<dim3(9, 64), 256, 0, stream>>>(qkvb, obufb);
    // F_enh = o @ opw^T + opb + F -> bf16, 576 blocks
    gemm_6464<true, true><<<dim3(8, 72), 256, 0, stream>>>(obufb, opwbf, opb, F, fenhb, BNR, 512, 512);
    // h_raw = F_enh @ w1^T + b1 -> fp32, 576 blocks
    gemm_6464<false, false><<<dim3(8, 72), 256, 0, stream>>>(fenhb, w1bf, b1, nullptr, hbuf, BNR, 512, 512);
    // LN+GELU + comp + exact top-51 + direct sparse write (fused, 2 rows/block)
    outer_topk<<<2304, 256, 0, stream>>>(F, hbuf, lng, lnb, w2, b2, tmpl, (float*)d_out);
}

// Round 7
// 287.658 us; speedup vs baseline: 1.0408x; 1.0408x over previous
//
#include <hip/hip_runtime.h>
#include <math.h>

#define NNB   576          // sequence length N
#define BNR   4608         // B*N rows
#define KSEL  51           // top-k along D

typedef unsigned short u16;
typedef __attribute__((ext_vector_type(8))) short bf16x8;
typedef __attribute__((ext_vector_type(4))) float f32x4;

// round-to-nearest (ties up) f32 -> bf16; inputs are finite
__device__ __forceinline__ u16 f2bf(float f) {
    unsigned u = __float_as_uint(f);
    return (u16)((u + 0x8000u) >> 16);
}
__device__ __forceinline__ unsigned pack2(float a, float b) {
    unsigned ua = __float_as_uint(a), ub = __float_as_uint(b);
    return ((ua + 0x8000u) >> 16) | ((ub + 0x8000u) & 0xffff0000u);
}
// async global->LDS DMA, 16B per lane; LDS dst = base + lane*16 (wave-uniform base)
__device__ __forceinline__ void load_lds16(const void* gp, void* lp) {
    __builtin_amdgcn_global_load_lds((const __attribute__((address_space(1))) void*)gp,
                                     (__attribute__((address_space(3))) void*)lp, 16, 0, 0);
}
// full-wave64 sum via DPP (row_shr 1/2/4/8, bcast15, bcast31), result uniform
__device__ __forceinline__ float dpp_red_add_f(float x) {
    x += __int_as_float(__builtin_amdgcn_update_dpp(0, __float_as_int(x), 0x111, 0xf, 0xf, true));
    x += __int_as_float(__builtin_amdgcn_update_dpp(0, __float_as_int(x), 0x112, 0xf, 0xf, true));
    x += __int_as_float(__builtin_amdgcn_update_dpp(0, __float_as_int(x), 0x114, 0xf, 0xf, true));
    x += __int_as_float(__builtin_amdgcn_update_dpp(0, __float_as_int(x), 0x118, 0xf, 0xf, true));
    x += __int_as_float(__builtin_amdgcn_update_dpp(0, __float_as_int(x), 0x142, 0xa, 0xf, true));
    x += __int_as_float(__builtin_amdgcn_update_dpp(0, __float_as_int(x), 0x143, 0xc, 0xf, true));
    return __int_as_float(__builtin_amdgcn_readlane(__float_as_int(x), 63));
}
// wave-wide boolean count: v_cmp -> sgpr-pair ballot, counted on the SALU pipe
__device__ __forceinline__ int wave_cnt(bool p) {
    return __popcll(__ballot(p));
}

// ---------------------------------------------------------------------------
// Cast F, in_proj_w, out_proj_w, w1 to bf16 (segment boundaries block-aligned)
// ---------------------------------------------------------------------------
__global__ __launch_bounds__(256)
void cast_bf16(const float* __restrict__ F, const float* __restrict__ ipw,
               const float* __restrict__ opw, const float* __restrict__ w1,
               u16* __restrict__ Fb, u16* __restrict__ ipwb,
               u16* __restrict__ opwb, u16* __restrict__ w1b)
{
    size_t i4 = ((size_t)blockIdx.x * 256 + threadIdx.x) * 4;
    const float* src; u16* dst; size_t off;
    if      (i4 < 2359296) { src = F;   dst = Fb;   off = i4; }
    else if (i4 < 3145728) { src = ipw; dst = ipwb; off = i4 - 2359296; }
    else if (i4 < 3407872) { src = opw; dst = opwb; off = i4 - 3145728; }
    else                   { src = w1;  dst = w1b;  off = i4 - 3407872; }
    float4 v = *(const float4*)(src + off);
    uint2 o; o.x = pack2(v.x, v.y); o.y = pack2(v.z, v.w);
    *(uint2*)(dst + off) = o;
}

// ---------------------------------------------------------------------------
// qkv GEMM: bf16 MFMA, 128x128 tile, BK=64. 4 waves in 2x2, each owns a
// 64x64 sub-tile (4x4 fragments, 32 MFMA per K-step). Grid 432 blocks.
// Cols<512 scaled by log2(e)/8 (attention prescale, exp2 downstream).
// ---------------------------------------------------------------------------
__global__ __launch_bounds__(256, 2)
void gemm_qkv128(const u16* __restrict__ A, const u16* __restrict__ Bw,
                 const float* __restrict__ bias, u16* __restrict__ C,
                 int Nc, int Kd)
{
    __shared__ uint4 As4[1024];          // 128 rows x 64 k bf16 = 16 KB
    __shared__ uint4 Bs4[1024];
    const int tid = threadIdx.x;
    const int lane = tid & 63, w = tid >> 6;
    const int wu = __builtin_amdgcn_readfirstlane(w);
    const int r16 = lane & 15, quad = lane >> 4;
    const int wy = w >> 1, wx = w & 1;
    const int c0 = blockIdx.x << 7, r0 = blockIdx.y << 7;

    const u16* pA[4]; const u16* pB[4];
    #pragma unroll
    for (int rd = 0; rd < 4; ++rd) {
        const int c = (rd << 8) + tid;            // 0..1023
        const int kb = c >> 9, g = (c >> 6) & 7, rr = (c >> 2) & 15, q = c & 3;
        const int row = (g << 4) + rr;
        const int koff = (kb << 5) + (q << 3);
        pA[rd] = A  + (size_t)(r0 + row) * Kd + koff;
        pB[rd] = Bw + (size_t)(c0 + row) * Kd + koff;
    }

    f32x4 acc[4][4];
    #pragma unroll
    for (int i = 0; i < 4; ++i)
        #pragma unroll
        for (int j = 0; j < 4; ++j) acc[i][j] = (f32x4){0.f, 0.f, 0.f, 0.f};

    for (int kk = 0; kk < Kd; kk += 64) {
        __syncthreads();
        #pragma unroll
        for (int rd = 0; rd < 4; ++rd) {
            load_lds16(pA[rd] + kk, (void*)(As4 + (rd << 8) + (wu << 6)));
            load_lds16(pB[rd] + kk, (void*)(Bs4 + (rd << 8) + (wu << 6)));
        }
        __syncthreads();
        #pragma unroll
        for (int kb = 0; kb < 2; ++kb) {
            bf16x8 af[4], bfr[4];
            #pragma unroll
            for (int i = 0; i < 4; ++i)
                af[i] = *(const bf16x8*)&As4[((kb * 8 + (wy << 2) + i) << 6) + (r16 << 2) + quad];
            #pragma unroll
            for (int j = 0; j < 4; ++j)
                bfr[j] = *(const bf16x8*)&Bs4[((kb * 8 + (wx << 2) + j) << 6) + (r16 << 2) + quad];
            #pragma unroll
            for (int i = 0; i < 4; ++i)
                #pragma unroll
                for (int j = 0; j < 4; ++j)
                    acc[i][j] = __builtin_amdgcn_mfma_f32_16x16x32_bf16(af[i], bfr[j], acc[i][j], 0, 0, 0);
        }
    }

    float bcol[4], scl[4];
    #pragma unroll
    for (int j = 0; j < 4; ++j) {
        const int col = c0 + (wx << 6) + (j << 4) + r16;
        bcol[j] = bias[col];
        scl[j] = (col < 512) ? 0.180336880111120426f : 1.0f;   // log2(e)/8
    }
    #pragma unroll
    for (int i = 0; i < 4; ++i) {
        #pragma unroll
        for (int reg = 0; reg < 4; ++reg) {
            const int row = r0 + (wy << 6) + (i << 4) + (quad << 2) + reg;
            const size_t base = (size_t)row * Nc;
            #pragma unroll
            for (int j = 0; j < 4; ++j) {
                const int col = c0 + (wx << 6) + (j << 4) + r16;
                float v = (acc[i][j][reg] + bcol[j]) * scl[j];
                C[base + col] = f2bf(v);
            }
        }
    }
}

// ---------------------------------------------------------------------------
// bf16 MFMA GEMM, 64x64 tile, BK=64: 576 blocks for the Nc=512 GEMMs.
// Waves 2x2, each 32x32 (2x2 frags, 16 acc VGPRs). Serial DMA staging.
// ---------------------------------------------------------------------------
template<bool RESID, bool OUT_BF16>
__global__ __launch_bounds__(256)
void gemm_6464(const u16* __restrict__ A, const u16* __restrict__ Bw,
               const float* __restrict__ bias, const float* __restrict__ res,
               void* __restrict__ Cv, int Mr, int Nc, int Kd)
{
    __shared__ uint4 As4[512];
    __shared__ uint4 Bs4[512];
    const int tid = threadIdx.x;
    const int lane = tid & 63, w = tid >> 6;
    const int wu = __builtin_amdgcn_readfirstlane(w);
    const int r16 = lane & 15, quad = lane >> 4;
    const int wy = w >> 1, wx = w & 1;
    const int r0 = blockIdx.y << 6, c0 = blockIdx.x << 6;

    const u16* pA[2]; const u16* pB[2];
    #pragma unroll
    for (int rd = 0; rd < 2; ++rd) {
        const int c = (rd << 8) + tid;            // 0..511
        const int kb = c >> 8, g = (c >> 6) & 3, rr = (c >> 2) & 15, q = c & 3;
        const int row = (g << 4) + rr;
        const int koff = (kb << 5) + (q << 3);
        pA[rd] = A  + (size_t)(r0 + row) * Kd + koff;
        pB[rd] = Bw + (size_t)(c0 + row) * Kd + koff;
    }

    f32x4 acc[2][2];
    #pragma unroll
    for (int i = 0; i < 2; ++i)
        #pragma unroll
        for (int j = 0; j < 2; ++j) acc[i][j] = (f32x4){0.f, 0.f, 0.f, 0.f};

    for (int kk = 0; kk < Kd; kk += 64) {
        __syncthreads();
        #pragma unroll
        for (int rd = 0; rd < 2; ++rd) {
            load_lds16(pA[rd] + kk, (void*)(As4 + (rd << 8) + (wu << 6)));
            load_lds16(pB[rd] + kk, (void*)(Bs4 + (rd << 8) + (wu << 6)));
        }
        __syncthreads();
        #pragma unroll
        for (int kb = 0; kb < 2; ++kb) {
            bf16x8 af[2], bfr[2];
            #pragma unroll
            for (int i = 0; i < 2; ++i)
                af[i] = *(const bf16x8*)&As4[((kb * 4 + (wy << 1) + i) << 6) + (r16 << 2) + quad];
            #pragma unroll
            for (int j = 0; j < 2; ++j)
                bfr[j] = *(const bf16x8*)&Bs4[((kb * 4 + (wx << 1) + j) << 6) + (r16 << 2) + quad];
            #pragma unroll
            for (int i = 0; i < 2; ++i)
                #pragma unroll
                for (int j = 0; j < 2; ++j)
                    acc[i][j] = __builtin_amdgcn_mfma_f32_16x16x32_bf16(af[i], bfr[j], acc[i][j], 0, 0, 0);
        }
    }

    float bcol[2];
    #pragma unroll
    for (int j = 0; j < 2; ++j) bcol[j] = bias[c0 + (wx << 5) + (j << 4) + r16];
    #pragma unroll
    for (int i = 0; i < 2; ++i) {
        #pragma unroll
        for (int reg = 0; reg < 4; ++reg) {
            const int row = r0 + (wy << 5) + (i << 4) + (quad << 2) + reg;
            const size_t base = (size_t)row * Nc;
            #pragma unroll
            for (int j = 0; j < 2; ++j) {
                const int col = c0 + (wx << 5) + (j << 4) + r16;
                float v = acc[i][j][reg] + bcol[j];
                if (RESID) v += res[base + col];
                if (OUT_BF16) ((u16*)Cv)[base + col] = f2bf(v);
                else          ((float*)Cv)[base + col] = v;
            }
        }
    }
}

// ---------------------------------------------------------------------------
// bf16 MFMA flash attention, no-max softmax (q prescaled by log2e/8 -> exp2).
// K via DMA. V scatter paired as ds_write_b32; Vfs XOR-swizzled, Pfs
// digit-permuted (both <=4-way conflicts).
// ---------------------------------------------------------------------------
__global__ __launch_bounds__(256)
void attn_mfma(const u16* __restrict__ qkv, u16* __restrict__ obuf)
{
    __shared__ uint4 Qf[512];
    __shared__ uint4 Kf[512];
    __shared__ u16  Vfs[4096];
    __shared__ u16  Pfs[4096];
    const int tid = threadIdx.x;
    const int lane = tid & 63, w = tid >> 6;
    const int wu = __builtin_amdgcn_readfirstlane(w);
    const int r16 = lane & 15, quad = lane >> 4;
    const int b = blockIdx.y >> 3, h = blockIdx.y & 7;
    const int i0 = blockIdx.x << 6;
    const u16* qb = qkv + (size_t)b * NNB * 1536 + h * 64;

    #pragma unroll
    for (int s = 0; s < 2; ++s) {        // stage Q once
        const int linear = (s << 8) + tid;
        const int r = linear >> 3, q7 = linear & 7;
        uint4 v = *(const uint4*)(qb + (size_t)(i0 + r) * 1536 + (q7 << 3));
        Qf[(((q7 >> 2) * 4 + (r >> 4)) << 6) + ((r & 15) << 2) + (q7 & 3)] = v;
    }
    const u16* pK[2];
    #pragma unroll
    for (int rd = 0; rd < 2; ++rd) {
        const int c = (rd << 8) + tid;
        const int kb = c >> 8, g = (c >> 6) & 3, rr = (c >> 2) & 15, q = c & 3;
        pK[rd] = qb + 512 + (size_t)((g << 4) + rr) * 1536 + (kb << 5) + (q << 3);
    }
    const int vp = tid >> 3, vq7 = tid & 7;     // V pair id / d-slice
    const int vj = vp << 1;
    const int vjl2 = (vj & 7) >> 1, vjq = (vj >> 3) & 3, vjkb = vj >> 5;

    float l_i[4] = {0.f, 0.f, 0.f, 0.f};
    f32x4 accO[4];
    #pragma unroll
    for (int f = 0; f < 4; ++f) accO[f] = (f32x4){0.f, 0.f, 0.f, 0.f};

    for (int j0 = 0; j0 < NNB; j0 += 64) {
        const u16* vbase = qb + 1024 + (size_t)(j0 + vj) * 1536 + (vq7 << 3);
        uint4 vA = *(const uint4*)vbase;
        uint4 vB = *(const uint4*)(vbase + 1536);
        __syncthreads();                 // previous iter's readers done
        load_lds16(pK[0] + (size_t)j0 * 1536, (void*)(Kf + (wu << 6)));
        load_lds16(pK[1] + (size_t)j0 * 1536, (void*)(Kf + 256 + (wu << 6)));
        {
            const u16* ea = (const u16*)&vA;
            const u16* eb = (const u16*)&vB;
            unsigned* V32 = (unsigned*)Vfs;
            #pragma unroll
            for (int e = 0; e < 8; ++e) {
                const int d = (vq7 << 3) + e;
                const int g = d >> 4;
                const int ch = ((vjkb * 4 + g) << 6) + ((((d & 15) << 2) + vjq) ^ g);
                V32[(ch << 2) + vjl2] = (unsigned)ea[e] | ((unsigned)eb[e] << 16);
            }
        }
        __syncthreads();

        f32x4 accS[4];
        #pragma unroll
        for (int f = 0; f < 4; ++f) accS[f] = (f32x4){0.f, 0.f, 0.f, 0.f};
        #pragma unroll
        for (int kb = 0; kb < 2; ++kb) {
            bf16x8 aq = *(const bf16x8*)&Qf[((kb * 4 + w) << 6) + (r16 << 2) + quad];
            #pragma unroll
            for (int f = 0; f < 4; ++f) {
                bf16x8 bk = *(const bf16x8*)&Kf[((kb * 4 + f) << 6) + (r16 << 2) + quad];
                accS[f] = __builtin_amdgcn_mfma_f32_16x16x32_bf16(aq, bk, accS[f], 0, 0, 0);
            }
        }
        #pragma unroll
        for (int reg = 0; reg < 4; ++reg) {
            const float s0 = exp2f(accS[0][reg]);
            const float s1 = exp2f(accS[1][reg]);
            const float s2 = exp2f(accS[2][reg]);
            const float s3 = exp2f(accS[3][reg]);
            l_i[reg] += (s0 + s1) + (s2 + s3);
            const int m = (quad << 2) + reg;
            const int sm = ((m & 3) << 2) + (m >> 2);     // digit-permuted m
            const float pv[4] = {s0, s1, s2, s3};
            #pragma unroll
            for (int f = 0; f < 4; ++f) {
                const int k = (f << 4) + r16;
                const int ch = (((k >> 5) * 4 + w) << 6) + (((k >> 3) & 3) << 4) + sm;
                Pfs[(ch << 3) + (k & 7)] = f2bf(pv[f]);
            }
        }
        #pragma unroll
        for (int kb = 0; kb < 2; ++kb) {
            bf16x8 ap = *(const bf16x8*)&Pfs[((((kb * 4 + w) << 6) + (quad << 4) + ((r16 & 3) << 2) + (r16 >> 2)) << 3)];
            #pragma unroll
            for (int f = 0; f < 4; ++f) {
                bf16x8 bv = *(const bf16x8*)&Vfs[((((kb * 4 + f) << 6) + (((r16 << 2) + quad) ^ f)) << 3)];
                accO[f] = __builtin_amdgcn_mfma_f32_16x16x32_bf16(ap, bv, accO[f], 0, 0, 0);
            }
        }
    }
    #pragma unroll
    for (int reg = 0; reg < 4; ++reg) {
        float l = l_i[reg];
        l += __shfl_xor(l, 1); l += __shfl_xor(l, 2);
        l += __shfl_xor(l, 4); l += __shfl_xor(l, 8);
        const float inv = 1.0f / l;
        const size_t row = (size_t)(b * NNB + i0 + (w << 4) + (quad << 2) + reg);
        #pragma unroll
        for (int f = 0; f < 4; ++f)
            obuf[row * 512 + (h << 6) + (f << 4) + r16] = f2bf(accO[f][reg] * inv);
    }
}

// ---------------------------------------------------------------------------
// Fused: LN+GELU -> comp -> exact top-51 -> direct sparse write.
// 4 waves x 4 m (r2 best-measured structure). NEW: bisection processes TWO
// bits per round (3 parallel candidate counts + 1 SALU resolution), halving
// the serial ballot-round depth (phase A 8->4, phase B <=32-><=16) that the
// r2/r3/r6 counter triangulation identified as the dominant stall (total
// VALU-issue invariant at ~45us while wall time 100-124us; stall hidden by
// neither TLP nor ILP => serial cross-pipe chain). Thresholds converge to
// identical pref/U/blo/prefk -> output bit-identical.
// ---------------------------------------------------------------------------
__global__ __launch_bounds__(256)
void outer_topk(const float* __restrict__ F, const float* __restrict__ hraw,
                const float* __restrict__ lng, const float* __restrict__ lnb,
                const float* __restrict__ w2, const float* __restrict__ b2,
                const float* __restrict__ T, float* __restrict__ out)
{
    const int bn = blockIdx.x;
    const int tid = threadIdx.x;
    const int lane = tid & 63, w = tid >> 6;
    __shared__ float Fr[512];
    __shared__ float Hr[512];
    __shared__ unsigned keyslots[4][4][64];
    __shared__ float redsm[8];

    // --- load F row + raw h row; LN + exact GELU into Hr ---
    if (tid < 128)
        *(float4*)&Fr[tid << 2] = *(const float4*)(F + (size_t)bn * 512 + (tid << 2));
    const float* hp = hraw + (size_t)bn * 512;
    float x0 = hp[tid], x1 = hp[tid + 256];
    float sw = dpp_red_add_f(x0 + x1);
    float sqw = dpp_red_add_f(x0 * x0 + x1 * x1);
    if (lane == 0) { redsm[w] = sw; redsm[4 + w] = sqw; }
    __syncthreads();
    const float s  = redsm[0] + redsm[1] + redsm[2] + redsm[3];
    const float sq = redsm[4] + redsm[5] + redsm[6] + redsm[7];
    const float mean = s * (1.0f / 512.0f);
    const float var  = sq * (1.0f / 512.0f) - mean * mean;
    const float rstd = rsqrtf(var + 1e-5f);
    float y = (x0 - mean) * rstd * lng[tid] + lnb[tid];
    Hr[tid] = 0.5f * y * (1.0f + erff(y * 0.70710678118654752f));
    y = (x1 - mean) * rstd * lng[tid + 256] + lnb[tid + 256];
    Hr[tid + 256] = 0.5f * y * (1.0f + erff(y * 0.70710678118654752f));
    __syncthreads();

    // --- comp[m] = Hr . w2[m] + b2[m]; DPP reduce, uniform in all lanes ---
    const int m0 = w << 2;
    float cm[4];
    #pragma unroll
    for (int mi = 0; mi < 4; ++mi) {
        const float* w2p = w2 + (size_t)(m0 + mi) * 512;
        float p = 0.f;
        #pragma unroll
        for (int t = 0; t < 8; ++t) p += Hr[lane + (t << 6)] * w2p[lane + (t << 6)];
        cm[mi] = dpp_red_add_f(p) + b2[m0 + mi];
    }

    // --- abs bit patterns + sign mask (exact fp32 op order of reference) ---
    unsigned u[4][8]; unsigned smask[4];
    #pragma unroll
    for (int mi = 0; mi < 4; ++mi) {
        smask[mi] = 0u;
        const float* Tp = T + (size_t)(m0 + mi) * 512;
        #pragma unroll
        for (int t = 0; t < 8; ++t) {
            float pp = Fr[lane + (t << 6)] * Tp[lane + (t << 6)];
            float pc = pp * cm[mi];
            const unsigned bits = __float_as_uint(pc);
            u[mi][t] = bits & 0x7fffffffu;
            smask[mi] |= (bits >> 31) << t;
        }
    }

    // --- phase A: bisect exponent bits 30..23, TWO bits per round.
    //     Invariant after settling down to bit L: cntP = count(u>=pref) >= K,
    //     U = count(u >= pref + (1<<L)). 3 candidate counts/round, parallel.
    unsigned pref[4] = {0u, 0u, 0u, 0u};
    int cntP[4] = {512, 512, 512, 512};
    int U[4] = {0, 0, 0, 0};
    for (int bit = 29; bit >= 23; bit -= 2) {    // pairs (30,29)..(24,23)
        #pragma unroll
        for (int mi = 0; mi < 4; ++mi) {
            const unsigned c3 = pref[mi] | (3u << bit);
            const unsigned c2 = pref[mi] | (2u << bit);
            const unsigned c1 = pref[mi] | (1u << bit);
            int n3 = 0, n2 = 0, n1 = 0;
            #pragma unroll
            for (int t = 0; t < 8; ++t) {
                const unsigned uv = u[mi][t];
                n3 += wave_cnt(uv >= c3);
                n2 += wave_cnt(uv >= c2);
                n1 += wave_cnt(uv >= c1);
            }
            if      (n3 >= KSEL) { pref[mi] = c3; cntP[mi] = n3; }
            else if (n2 >= KSEL) { pref[mi] = c2; cntP[mi] = n2; U[mi] = n3; }
            else if (n1 >= KSEL) { pref[mi] = c1; cntP[mi] = n1; U[mi] = n2; }
            else                 {                               U[mi] = n1; }
        }
    }
    // rare: extend bisection (1-bit) until the tie bucket fits in 64 slots
    int blo[4];
    #pragma unroll
    for (int mi = 0; mi < 4; ++mi) {
        int b = 23;
        while ((cntP[mi] - U[mi]) > 64 && b > 0) {
            --b;
            const unsigned cand = pref[mi] | (1u << b);
            int cnt = 0;
            #pragma unroll
            for (int t = 0; t < 8; ++t) cnt += wave_cnt(u[mi][t] >= cand);
            if (cnt >= KSEL) { pref[mi] = cand; cntP[mi] = cnt; } else U[mi] = cnt;
        }
        blo[mi] = b;
    }
    int need[4]; bool done[4];
    #pragma unroll
    for (int mi = 0; mi < 4; ++mi) {
        need[mi] = KSEL - U[mi];
        done[mi] = (need[mi] == cntP[mi] - U[mi]);   // whole bucket selected
    }

    // --- compact tie bucket into distinct 32-bit keys, one slot per lane ---
    const unsigned long long lmask = (1ull << lane) - 1ull;
    unsigned kv[4] = {0u, 0u, 0u, 0u};
    #pragma unroll
    for (int mi = 0; mi < 4; ++mi) {
        if (done[mi]) continue;
        keyslots[w][mi][lane] = 0u;
        const int bl = blo[mi];
        const unsigned lowmask = (1u << bl) - 1u;
        int running = 0;
        #pragma unroll
        for (int t = 0; t < 8; ++t) {
            const bool tie = ((u[mi][t] ^ pref[mi]) >> bl) == 0u;
            const unsigned long long M = __ballot(tie);
            const int slot = running + __popcll(M & lmask);
            if (tie && slot < 64) {
                const unsigned key = ((u[mi][t] & lowmask) << 9) | (unsigned)(511 - ((t << 6) + lane));
                keyslots[w][mi][slot] = key;
            }
            running += __popcll(M);
        }
        kv[mi] = keyslots[w][mi][lane];
    }

    // --- phase B: bisect keys, TWO bits per round (3 parallel ballots),
    //     early exit on exact count. Same converged prefk as 1-bit. ---
    unsigned prefk[4] = {0u, 0u, 0u, 0u};
    for (int bb = 30; bb >= 0; bb -= 2) {        // pairs (31,30)..(1,0)
        if (done[0] & done[1] & done[2] & done[3]) break;
        #pragma unroll
        for (int mi = 0; mi < 4; ++mi) {
            if (done[mi]) continue;
            const unsigned c3 = prefk[mi] | (3u << bb);
            const unsigned c2 = prefk[mi] | (2u << bb);
            const unsigned c1 = prefk[mi] | (1u << bb);
            const unsigned kvm = kv[mi];
            const int n3 = __popcll(__ballot(kvm >= c3));
            const int n2 = __popcll(__ballot(kvm >= c2));
            const int n1 = __popcll(__ballot(kvm >= c1));
            if      (n3 >= need[mi]) { prefk[mi] = c3; if (n3 == need[mi]) done[mi] = true; }
            else if (n2 >= need[mi]) { prefk[mi] = c2; if (n2 == need[mi]) done[mi] = true; }
            else if (n1 >= need[mi]) { prefk[mi] = c1; if (n1 == need[mi]) done[mi] = true; }
        }
    }

    // --- per-wave direct write of its 4 m-columns (bit-exact values) ---
    float* ob = out + (size_t)bn * 8192 + m0;
    #pragma unroll
    for (int t = 0; t < 8; ++t) {
        const int d = (t << 6) + lane;
        float4 v;
        float* vv = &v.x;
        #pragma unroll
        for (int mi = 0; mi < 4; ++mi) {
            const unsigned uu = u[mi][t];
            const int bl = blo[mi];
            const bool tie = ((uu ^ pref[mi]) >> bl) == 0u;
            const unsigned key = ((uu & ((1u << bl) - 1u)) << 9) | (unsigned)(511 - d);
            const bool sel = (uu >= pref[mi] + (1u << bl)) || (tie && key >= prefk[mi]);
            const unsigned bits = uu | (((smask[mi] >> t) & 1u) << 31);
            vv[mi] = sel ? __uint_as_float(bits) : 0.0f;
        }
        *(float4*)(ob + (size_t)d * 16) = v;
    }
}

// ---------------------------------------------------------------------------
extern "C" void kernel_launch(void* const* d_in, const int* in_sizes, int n_in,
                              void* d_out, int out_size, void* d_ws, size_t ws_size,
                              hipStream_t stream)
{
    const float* F    = (const float*)d_in[0];
    const float* ipw  = (const float*)d_in[1];
    const float* ipb  = (const float*)d_in[2];
    const float* opw  = (const float*)d_in[3];
    const float* opb  = (const float*)d_in[4];
    const float* w1   = (const float*)d_in[5];
    const float* b1   = (const float*)d_in[6];
    const float* lng  = (const float*)d_in[7];
    const float* lnb  = (const float*)d_in[8];
    const float* w2   = (const float*)d_in[9];
    const float* b2   = (const float*)d_in[10];
    const float* tmpl = (const float*)d_in[11];

    char* wsb = (char*)d_ws;
    u16*   qkvb  = (u16*)wsb;                     // 4608*1536 bf16
    u16*   obufb = (u16*)(wsb + 14155776);        // 4608*512 bf16
    u16*   fenhb = (u16*)(wsb + 18874368);        // 4608*512 bf16
    float* hbuf  = (float*)(wsb + 23592960);      // 4608*512 f32 (raw, pre-LN)
    u16*   Fbf   = (u16*)(wsb + 33030144);        // 4608*512 bf16
    u16*   ipwbf = (u16*)(wsb + 37748736);        // 1536*512 bf16
    u16*   opwbf = (u16*)(wsb + 39321600);        // 512*512 bf16
    u16*   w1bf  = (u16*)(wsb + 39845888);        // 512*512 bf16

    cast_bf16<<<3584, 256, 0, stream>>>(F, ipw, opw, w1, Fbf, ipwbf, opwbf, w1bf);
    // qkv = F @ ipw^T + ipb (q prescaled by log2e/8) -> bf16, 432 blocks
    gemm_qkv128<<<dim3(12, 36), 256, 0, stream>>>(Fbf, ipwbf, ipb, qkvb, 1536, 512);
    // o = attention(qkv) -> bf16 [4608,512]
    attn_mfma<<<dim3(9, 64), 256, 0, stream>>>(qkvb, obufb);
    // F_enh = o @ opw^T + opb + F -> bf16, 576 blocks
    gemm_6464<true, true><<<dim3(8, 72), 256, 0, stream>>>(obufb, opwbf, opb, F, fenhb, BNR, 512, 512);
    // h_raw = F_enh @ w1^T + b1 -> fp32, 576 blocks
    gemm_6464<false, false><<<dim3(8, 72), 256, 0, stream>>>(fenhb, w1bf, b1, nullptr, hbuf, BNR, 512, 512);
    // LN+GELU + comp + exact top-51 (2-bit bisection) + direct sparse write
    outer_topk<<<4608, 256, 0, stream>>>(F, hbuf, lng, lnb, w2, b2, tmpl, (float*)d_out);
}